// Round 1
// baseline (84.455 us; speedup 1.0000x reference)
//
#include <hip/hip_runtime.h>

// Problem constants (from reference): x (8192,64) f32, x_var (8192,64) f32,
// proto_mean (19,10,64) f32, proto_var (19,10,64) f32 -> out (8192,19,10) f32.
#define NROWS 8192
#define KDIM 64
#define CDIM 19
#define MDIM 10
#define CMDIM (CDIM * MDIM)        // 190
#define CM_PER_BLOCK 19            // one 'c' worth per block.y... actually 19 consecutive cm
#define ROWS_PER_BLOCK 64
#define LDS_STRIDE 65              // pad to break k*64 bank alias

__global__ __launch_bounds__(256)
void probproto_kernel(const float* __restrict__ x,
                      const float* __restrict__ xv,
                      const float* __restrict__ pm,
                      const float* __restrict__ pv,
                      float* __restrict__ out)
{
    __shared__ float xs_t[KDIM * LDS_STRIDE];   // [k][n_local], transposed
    __shared__ float xvs_t[KDIM * LDS_STRIDE];
    __shared__ float pms[CM_PER_BLOCK * KDIM];
    __shared__ float pvs[CM_PER_BLOCK * KDIM];

    const int t   = threadIdx.x;
    const int n0  = blockIdx.x * ROWS_PER_BLOCK;
    const int cm0 = blockIdx.y * CM_PER_BLOCK;

    // ---- stage x / x_var tile (64 rows x 64 k), transposed into LDS ----
    // 1024 float4 per array; 256 threads -> 4 float4 each, coalesced.
    const float4* x4  = (const float4*)(x  + (size_t)n0 * KDIM);
    const float4* xv4 = (const float4*)(xv + (size_t)n0 * KDIM);
    #pragma unroll
    for (int i = 0; i < 4; ++i) {
        int idx = t + 256 * i;        // [0, 1024)
        int r   = idx >> 4;           // local row 0..63
        int c4  = idx & 15;           // float4 column
        float4 a = x4[idx];
        float4 b = xv4[idx];
        int k = c4 * 4;
        xs_t[(k + 0) * LDS_STRIDE + r] = a.x;
        xs_t[(k + 1) * LDS_STRIDE + r] = a.y;
        xs_t[(k + 2) * LDS_STRIDE + r] = a.z;
        xs_t[(k + 3) * LDS_STRIDE + r] = a.w;
        xvs_t[(k + 0) * LDS_STRIDE + r] = b.x;
        xvs_t[(k + 1) * LDS_STRIDE + r] = b.y;
        xvs_t[(k + 2) * LDS_STRIDE + r] = b.z;
        xvs_t[(k + 3) * LDS_STRIDE + r] = b.w;
    }
    // ---- stage this block's 19 prototypes (pm, pv) ----
    for (int idx = t; idx < CM_PER_BLOCK * KDIM; idx += 256) {
        pms[idx] = pm[cm0 * KDIM + idx];
        pvs[idx] = pv[cm0 * KDIM + idx];
    }
    __syncthreads();

    const int wave = t >> 6;
    const int lane = t & 63;
    const int n    = n0 + lane;       // lane <-> row

    // Each wave handles cm indices wave, wave+4, ... within the 19-cm tile.
    for (int cmi = wave; cmi < CM_PER_BLOCK; cmi += 4) {
        float accQ = 0.0f;            // sum of d^2 / v
        float accL = 0.0f;            // sum of log2(v) via chunked products
        for (int kc = 0; kc < 4; ++kc) {
            float prod = 1.0f;
            #pragma unroll
            for (int k8 = 0; k8 < 16; ++k8) {
                int k = kc * 16 + k8;
                float pmv = pms[cmi * KDIM + k];     // wave-uniform -> broadcast
                float pvv = pvs[cmi * KDIM + k];
                float xx  = xs_t[k * LDS_STRIDE + lane];
                float xvv = xvs_t[k * LDS_STRIDE + lane];
                float v = xvv + pvv;
                float d = pmv - xx;
                accQ = fmaf(d * d, __builtin_amdgcn_rcpf(v), accQ);
                prod *= v;            // v in [1,2) here; chunk of 16 stays < 2^16
            }
            accL += __log2f(prod);    // ln via log2: one log per 16 k
        }
        // -0.5 * mean over K: -(accQ + ln2*accL) / 128
        out[(size_t)n * CMDIM + cm0 + cmi] =
            -(accQ + 0.69314718055994531f * accL) * (1.0f / 128.0f);
    }
}

extern "C" void kernel_launch(void* const* d_in, const int* in_sizes, int n_in,
                              void* d_out, int out_size, void* d_ws, size_t ws_size,
                              hipStream_t stream) {
    const float* x  = (const float*)d_in[0];
    const float* xv = (const float*)d_in[1];
    const float* pm = (const float*)d_in[2];
    const float* pv = (const float*)d_in[3];
    float* out = (float*)d_out;

    dim3 grid(NROWS / ROWS_PER_BLOCK, CMDIM / CM_PER_BLOCK);  // 128 x 10
    probproto_kernel<<<grid, 256, 0, stream>>>(x, xv, pm, pv, out);
}